// Round 16
// baseline (42.525 us; speedup 1.0000x reference)
//
#include <hip/hip_runtime.h>
#include <math.h>

// DIAGNOSTIC ROUND (R16): v15 (x8-replicated window table) body at nrep=4 via
// opaque-zero perturbation -- the A/B against R14 (R13 body, nrep=4, conflict
// counter 1.174e7). Purpose: read SQ_LDS_BANK_CONFLICT for the replicated
// table. Counter halved + slope unchanged -> conflicts were never critical
// path -> restore R13 and declare. Counter unchanged -> replication scheme
// broken -> fix addressing next round.

#define LOG2E 1.4426950408889634f
#define EPSF  1e-8f
#define TSC   2048.0f
#define HB    376
#define SPANM 753
#define BLOCK 512
#define PPB   64
#define SSTR  52

#define DPP_ADD(X, CTRL)                                                   \
    (X) += __int_as_float(__builtin_amdgcn_mov_dpp(                        \
               __float_as_int(X), (CTRL), 0xf, 0xf, false));

__global__ __launch_bounds__(BLOCK, 8) void voronoi_v16d(
    const float* __restrict__ points,
    const float* __restrict__ seeds,
    const float* __restrict__ w_raw,
    const float* __restrict__ theta,
    const float* __restrict__ a_raw,
    float* __restrict__ out,
    int N, int nrep)
{
    __shared__ float    s_tab[SPANM * 8];
    __shared__ unsigned s_sl[PPB * SSTR];
    __shared__ float    s_su[32], s_sv[32], s_m00[32], s_m01[32], s_m11[32];

    const int t = threadIdx.x;

    const float wr = w_raw[0];
    const float sg = __builtin_amdgcn_rcpf(1.0f + exp2f(wr * (-LOG2E / 5.0f)));
    const float w  = 0.005f + 0.495f * sg;

    const int icent = (int)fmaf(w, TSC, 0.5f);
    const int T1    = icent > HB ? icent - HB : 0;
    const int SPAN  = (icent + HB + 1) - T1;

    if (t < 32) {
        const float x  = a_raw[t];
        const float z  = exp2f(2.0f * LOG2E * x);
        const float th = (z - 1.0f) * __builtin_amdgcn_rcpf(z + 1.0f);
        const float a  = 0.75f * th + 1.25f;
        const float ia = __builtin_amdgcn_rcpf(a + EPSF);
        const float cs = __cosf(theta[t]);
        const float sn = __sinf(theta[t]);
        const float S2 = TSC * TSC;
        s_m00[t] = (a * cs * cs + ia * sn * sn) * S2;
        s_m01[t] = (2.0f * cs * sn * (ia - a)) * S2;
        s_m11[t] = (a * sn * sn + ia * cs * cs) * S2;
        s_su[t]  = seeds[2 * t];
        s_sv[t]  = seeds[2 * t + 1];
    }
    for (int k = t; k < SPAN; k += BLOCK) {
        const float arg = fmaf(-(float)(T1 + k), 50.0f / TSC, 50.0f * w);
        const float val = __builtin_amdgcn_rcpf(1.0f + exp2f(-arg * LOG2E));
        float4 v4; v4.x = val; v4.y = val; v4.z = val; v4.w = val;
        float4* dst = (float4*)&s_tab[k << 3];
        dst[0] = v4; dst[1] = v4;
    }
    __syncthreads();

    const int pb = t >> 3;
    const int g  = t & 7;
    const int s0 = g * 4;
    const int p  = blockIdx.x * PPB + pb;
    if (p >= N) return;

    const int c4   = (t & 7) << 2;
    const int adjB = c4 - (T1 << 5);
    const int loA  = c4;
    const int hiA  = ((SPAN - 1) << 5) + c4;

    const float4 su4  = *(const float4*)&s_su[s0];
    const float4 sv4  = *(const float4*)&s_sv[s0];
    const float4 m004 = *(const float4*)&s_m00[s0];
    const float4 m014 = *(const float4*)&s_m01[s0];
    const float4 m114 = *(const float4*)&s_m11[s0];

    const float2 uv = ((const float2*)points)[p];

    float zero;
    asm volatile("v_mov_b32 %0, 0" : "=v"(zero));

    unsigned* row = &s_sl[pb * SSTR];
    const char* tb = (const char*)s_tab;
    const float EPS_Q = 1e-8f * TSC * TSC;
    const float cE = -(20.0f * LOG2E) / TSC;

    for (int rep = 0; rep < nrep; ++rep) {
        const float u = fmaf((float)rep, zero, uv.x);
        const float v = fmaf((float)rep, zero, uv.y);

        float4 d4;
#define DIST(SU, SV, M00, M01, M11, OUTD)                                  \
        {                                                                  \
            float du = u - (SU); du -= rintf(du);                          \
            float dv = v - (SV); dv -= rintf(dv);                          \
            float q = fmaf(du * du, (M00),                                 \
                      fmaf(du * dv, (M01),                                 \
                      fmaf(dv * dv, (M11), EPS_Q)));                       \
            (OUTD) = sqrtf(q);                                             \
        }
        DIST(su4.x, sv4.x, m004.x, m014.x, m114.x, d4.x)
        DIST(su4.y, sv4.y, m004.y, m014.y, m114.y, d4.y)
        DIST(su4.z, sv4.z, m004.z, m014.z, m114.z, d4.z)
        DIST(su4.w, sv4.w, m004.w, m014.w, m114.w, d4.w)

        float4 e4;
        e4.x = exp2f(d4.x * cE);
        e4.y = exp2f(d4.y * cE);
        e4.z = exp2f(d4.z * cE);
        e4.w = exp2f(d4.w * cE);
        float Z = (e4.x + e4.y) + (e4.z + e4.w);
        DPP_ADD(Z, 0xB1)
        DPP_ADD(Z, 0x4E)
        Z += __shfl_xor(Z, 4, 64);
        const float rcpZ = __builtin_amdgcn_rcpf(Z);
        float4 w4;
        w4.x = e4.x * rcpZ; w4.y = e4.y * rcpZ;
        w4.z = e4.z * rcpZ; w4.w = e4.w * rcpZ;
        float sq = w4.x * w4.x;
        sq = fmaf(w4.y, w4.y, sq);
        sq = fmaf(w4.z, w4.z, sq);
        sq = fmaf(w4.w, w4.w, sq);

        int i0 = (int)(d4.x + 0.5f);
        int i1 = (int)(d4.y + 0.5f);
        int i2 = (int)(d4.z + 0.5f);
        int i3 = (int)(d4.w + 0.5f);

        {
            uint2 pk;
            pk.x = (unsigned)i0 | ((unsigned)i1 << 16);
            pk.y = (unsigned)i2 | ((unsigned)i3 << 16);
            *(uint2*)(row + 2 * g) = pk;
            *(float4*)(row + 16 + 4 * g) = w4;
        }

#define TB(IA, IB, WJ, ACC)                                                \
        {                                                                  \
            const int hi = (IA) > (IB) ? (IA) : (IB);                      \
            const int lo = (IA) > (IB) ? (IB) : (IA);                      \
            int a = ((hi - lo) << 5) + adjB;                               \
            a = a > loA ? a : loA;                                         \
            a = a < hiA ? a : hiA;                                         \
            const float B = *(const float*)(tb + a);                       \
            (ACC) = fmaf((WJ), B, (ACC));                                  \
        }

        float b0, b1, b2, b3;
        b0 = 0.0f; b1 = 0.0f; b2 = 0.0f; b3 = 0.0f;
        TB(i0, i1, w4.y, b0)
        TB(i0, i2, w4.z, b0)
        TB(i0, i3, w4.w, b0)
        TB(i1, i2, w4.z, b1)
        TB(i1, i3, w4.w, b1)
        TB(i2, i3, w4.w, b2)

#define ROT(R)                                                             \
        {                                                                  \
            const int gj = ((g + (R)) & 7);                                \
            const uint2  ip = *(const uint2*) (row + 2 * gj);              \
            const float4 wj = *(const float4*)(row + 16 + 4 * gj);         \
            const int j0 = (int)(ip.x & 0xffffu);                          \
            const int j1 = (int)(ip.x >> 16);                              \
            const int j2 = (int)(ip.y & 0xffffu);                          \
            const int j3 = (int)(ip.y >> 16);                              \
            TB(i0, j0, wj.x, b0)                                           \
            TB(i0, j1, wj.y, b0)                                           \
            TB(i0, j2, wj.z, b0)                                           \
            TB(i0, j3, wj.w, b0)                                           \
            TB(i1, j0, wj.x, b1)                                           \
            TB(i1, j1, wj.y, b1)                                           \
            TB(i1, j2, wj.z, b1)                                           \
            TB(i1, j3, wj.w, b1)                                           \
            TB(i2, j0, wj.x, b2)                                           \
            TB(i2, j1, wj.y, b2)                                           \
            TB(i2, j2, wj.z, b2)                                           \
            TB(i2, j3, wj.w, b2)                                           \
            TB(i3, j0, wj.x, b3)                                           \
            TB(i3, j1, wj.y, b3)                                           \
            TB(i3, j2, wj.z, b3)                                           \
            TB(i3, j3, wj.w, b3)                                           \
        }
        ROT(1)
        ROT(2)
        ROT(3)

        {
            const int gj = ((g + 4) & 7);
            const uint2  ip = *(const uint2*) (row + 2 * gj);
            const float4 wj = *(const float4*)(row + 16 + 4 * gj);
            const int j0 = (int)(ip.x & 0xffffu);
            const int j1 = (int)(ip.x >> 16);
            const int j2 = (int)(ip.y & 0xffffu);
            const int j3 = (int)(ip.y >> 16);
            const bool lo4 = (g < 4);
            const int   cA0 = lo4 ? j0 : j2;
            const int   cA1 = lo4 ? j1 : j3;
            const float vA0 = lo4 ? wj.x : wj.z;
            const float vA1 = lo4 ? wj.y : wj.w;
            const int   cB0 = lo4 ? j2 : j0;
            const int   cB1 = lo4 ? j3 : j1;
            const float vB0 = lo4 ? wj.z : wj.x;
            const float vB1 = lo4 ? wj.w : wj.y;
            TB(i0, cA0, vA0, b0)
            TB(i0, cA1, vA1, b0)
            TB(i1, cA0, vA0, b1)
            TB(i1, cA1, vA1, b1)
            TB(i2, cB0, vB0, b2)
            TB(i2, cB1, vB1, b2)
            TB(i3, cB0, vB0, b3)
            TB(i3, cB1, vB1, b3)
        }

        float nb = w4.x * b0;
        nb = fmaf(w4.y, b1, nb);
        nb = fmaf(w4.z, b2, nb);
        nb = fmaf(w4.w, b3, nb);

        DPP_ADD(nb, 0xB1)
        DPP_ADD(sq, 0xB1)
        DPP_ADD(nb, 0x4E)
        DPP_ADD(sq, 0x4E)
        nb += __shfl_xor(nb, 4, 64);
        sq += __shfl_xor(sq, 4, 64);

        const float den   = fmaxf(0.5f * (1.0f - sq), 0.0f) + EPSF;
        const float ratio = nb * __builtin_amdgcn_rcpf(den);
        const float rho   = 1.0f - exp2f(ratio * (-8.0f * LOG2E));
        if (g == 0) out[p] = rho;
    }
}

extern "C" void kernel_launch(void* const* d_in, const int* in_sizes, int n_in,
                              void* d_out, int out_size, void* d_ws, size_t ws_size,
                              hipStream_t stream) {
    const float* points = (const float*)d_in[0];
    const float* seeds  = (const float*)d_in[1];
    const float* w_raw  = (const float*)d_in[2];
    const float* theta  = (const float*)d_in[3];
    const float* a_raw  = (const float*)d_in[4];
    float* out = (float*)d_out;

    const int N = in_sizes[0] / 2;
    const int grid = (N + PPB - 1) / PPB;

    voronoi_v16d<<<grid, BLOCK, 0, stream>>>(points, seeds, w_raw, theta,
                                             a_raw, out, N, 4);
}

// Round 17
// 15.326 us; speedup vs baseline: 2.7748x; 2.7748x over previous
//
#include <hip/hip_runtime.h>
#include <math.h>

// VoronoiDecoder: N=65536 x S=32. R13 geometry (8 lanes/pt, 4 seeds/lane,
// 512-thr blocks, grid=1024 = 4 blocks/CU) with the leanest pair body yet:
// d kept as FLOAT in table-entry units; table built HALF-ENTRY-SHIFTED
// (T[k] = sigma at (k+0.5)/TSC) so plain truncation == round-to-bin-midpoint.
// TB = v_sub_f32 + v_cvt_u32_f32(|x| free src-mod) + lshl + ds_read + fma
//    = 4 VALU + 1 DS per eval (R13 had 6). Full-range table @ TSC=2048
// (2049 entries, 8.4 KB; d <= 1.0 exactly since lam_max(M)=2, |diff|^2 <= 0.5)
// -> NO clamps anywhere. No int quantize step; d4 staged as float4.
// R16 A/B showed VALU is the critical pipe (78% busy) -- this cuts only VALU.

#define LOG2E 1.4426950408889634f
#define EPSF  1e-8f
#define TSC   2048.0f           // table entries per unit distance
#define TAB_N 2112              // 2049 used, padded
#define BLOCK 512
#define PPB   64                // points per block
#define SSTR  40                // slab row stride (words): 2-way banks = free

#define DPP_ADD(X, CTRL)                                                   \
    (X) += __int_as_float(__builtin_amdgcn_mov_dpp(                        \
               __float_as_int(X), (CTRL), 0xf, 0xf, false));

__global__ __launch_bounds__(BLOCK, 8) void voronoi_v17(
    const float* __restrict__ points,   // (N,2)
    const float* __restrict__ seeds,    // (32,2)
    const float* __restrict__ w_raw,    // (1,)
    const float* __restrict__ theta,    // (32,)
    const float* __restrict__ a_raw,    // (32,)
    float* __restrict__ out,            // (N,)
    int N)
{
    __shared__ float s_tab[TAB_N];
    __shared__ float s_dd[PPB * SSTR];
    __shared__ float s_ww[PPB * SSTR];
    __shared__ float s_su[32], s_sv[32], s_m00[32], s_m01[32], s_m11[32];

    const int t = threadIdx.x;

    // uniform band half-width
    const float wr = w_raw[0];
    const float sg = __builtin_amdgcn_rcpf(1.0f + exp2f(wr * (-LOG2E / 5.0f)));
    const float w  = 0.005f + 0.495f * sg;

    // seed metrics, pre-scaled so sqrt lands in entry units (2x folded in m01)
    if (t < 32) {
        const float x  = a_raw[t];
        const float z  = exp2f(2.0f * LOG2E * x);
        const float th = (z - 1.0f) * __builtin_amdgcn_rcpf(z + 1.0f);  // tanh
        const float a  = 0.75f * th + 1.25f;
        const float ia = __builtin_amdgcn_rcpf(a + EPSF);
        const float cs = __cosf(theta[t]);
        const float sn = __sinf(theta[t]);
        const float S2 = TSC * TSC;
        s_m00[t] = (a * cs * cs + ia * sn * sn) * S2;
        s_m01[t] = (2.0f * cs * sn * (ia - a)) * S2;
        s_m11[t] = (a * sn * sn + ia * cs * cs) * S2;
        s_su[t]  = seeds[2 * t];
        s_sv[t]  = seeds[2 * t + 1];
    }
    // half-entry-shifted band table: T[k] = sigmoid((w - (k+0.5)/TSC)/0.02)
    {
        const float kC = (50.0f * LOG2E) / TSC;
        const float kB = fmaf(-0.5f, kC, -w * (50.0f * LOG2E));
        for (int k = t; k < TAB_N; k += BLOCK) {
            const float y = exp2f(fmaf((float)k, kC, kB));
            s_tab[k] = __builtin_amdgcn_rcpf(1.0f + y);
        }
    }
    __syncthreads();   // only barrier; slab exchange below is same-wave

    const int pb = t >> 3;              // point slot (0..63)
    const int g  = t & 7;               // seed group
    const int s0 = g * 4;
    const int p  = blockIdx.x * PPB + pb;
    if (p >= N) return;

    const float4 su4  = *(const float4*)&s_su[s0];
    const float4 sv4  = *(const float4*)&s_sv[s0];
    const float4 m004 = *(const float4*)&s_m00[s0];
    const float4 m014 = *(const float4*)&s_m01[s0];
    const float4 m114 = *(const float4*)&s_m11[s0];

    const float2 uv = ((const float2*)points)[p];
    const float u = uv.x, v = uv.y;

    const float EPS_Q = 1e-8f * TSC * TSC;
    float4 d4;
#define DIST(SU, SV, M00, M01, M11, OUTD)                                  \
    {                                                                      \
        float du = u - (SU); du -= rintf(du);                              \
        float dv = v - (SV); dv -= rintf(dv);                              \
        float q = fmaf(du * du, (M00),                                     \
                  fmaf(du * dv, (M01),                                     \
                  fmaf(dv * dv, (M11), EPS_Q)));                           \
        (OUTD) = sqrtf(q);                                                 \
    }
    DIST(su4.x, sv4.x, m004.x, m014.x, m114.x, d4.x)
    DIST(su4.y, sv4.y, m004.y, m014.y, m114.y, d4.y)
    DIST(su4.z, sv4.z, m004.z, m014.z, m114.z, d4.z)
    DIST(su4.w, sv4.w, m004.w, m014.w, m114.w, d4.w)

    // softmax over 32 seeds (exponents bounded below ~ -29; no max-sub)
    const float cE = -(20.0f * LOG2E) / TSC;
    float4 e4;
    e4.x = exp2f(d4.x * cE);
    e4.y = exp2f(d4.y * cE);
    e4.z = exp2f(d4.z * cE);
    e4.w = exp2f(d4.w * cE);
    float Z = (e4.x + e4.y) + (e4.z + e4.w);
    DPP_ADD(Z, 0xB1)
    DPP_ADD(Z, 0x4E)
    Z += __shfl_xor(Z, 4, 64);
    const float rcpZ = __builtin_amdgcn_rcpf(Z);
    float4 w4;
    w4.x = e4.x * rcpZ; w4.y = e4.y * rcpZ;
    w4.z = e4.z * rcpZ; w4.w = e4.w * rcpZ;
    float sq = w4.x * w4.x;
    sq = fmaf(w4.y, w4.y, sq);
    sq = fmaf(w4.z, w4.z, sq);
    sq = fmaf(w4.w, w4.w, sq);

    // stage (d float4, w float4) to this point's slab row (same-wave)
    float* db = &s_dd[pb * SSTR];
    float* wb = &s_ww[pb * SSTR];
    *(float4*)(db + s0) = d4;
    *(float4*)(wb + s0) = w4;

    // pair eval: sub + cvt(|x|) + lshl + ds_read + fma  (no clamp, no round)
#define TB(DA, DB, WJ, ACC)                                                \
    {                                                                      \
        const float df = (DA) - (DB);                                      \
        const unsigned k = (unsigned)fabsf(df);                            \
        const float B = s_tab[k];                                          \
        (ACC) = fmaf((WJ), B, (ACC));                                      \
    }

    // 6 in-lane pairs
    float b0, b1, b2, b3;
    b0 = 0.0f; b1 = 0.0f; b2 = 0.0f; b3 = 0.0f;
    TB(d4.x, d4.y, w4.y, b0)
    TB(d4.x, d4.z, w4.z, b0)
    TB(d4.x, d4.w, w4.w, b0)
    TB(d4.y, d4.z, w4.z, b1)
    TB(d4.y, d4.w, w4.w, b1)
    TB(d4.z, d4.w, w4.w, b2)

#define ROT(R)                                                             \
    {                                                                      \
        const int gj = ((g + (R)) & 7) * 4;                                \
        const float4 dj = *(const float4*)(db + gj);                       \
        const float4 wj = *(const float4*)(wb + gj);                       \
        TB(d4.x, dj.x, wj.x, b0)                                           \
        TB(d4.x, dj.y, wj.y, b0)                                           \
        TB(d4.x, dj.z, wj.z, b0)                                           \
        TB(d4.x, dj.w, wj.w, b0)                                           \
        TB(d4.y, dj.x, wj.x, b1)                                           \
        TB(d4.y, dj.y, wj.y, b1)                                           \
        TB(d4.y, dj.z, wj.z, b1)                                           \
        TB(d4.y, dj.w, wj.w, b1)                                           \
        TB(d4.z, dj.x, wj.x, b2)                                           \
        TB(d4.z, dj.y, wj.y, b2)                                           \
        TB(d4.z, dj.z, wj.z, b2)                                           \
        TB(d4.z, dj.w, wj.w, b2)                                           \
        TB(d4.w, dj.x, wj.x, b3)                                           \
        TB(d4.w, dj.y, wj.y, b3)                                           \
        TB(d4.w, dj.z, wj.z, b3)                                           \
        TB(d4.w, dj.w, wj.w, b3)                                           \
    }
    ROT(1)
    ROT(2)
    ROT(3)

    // ROT(4): diag/anti-diag split -- exact single coverage, 8 evals/lane
    {
        const int gj = ((g + 4) & 7) * 4;
        const float4 dj = *(const float4*)(db + gj);
        const float4 wj = *(const float4*)(wb + gj);
        const bool lo4 = (g < 4);
        const float cA0 = lo4 ? dj.x : dj.z;
        const float cA1 = lo4 ? dj.y : dj.w;
        const float vA0 = lo4 ? wj.x : wj.z;
        const float vA1 = lo4 ? wj.y : wj.w;
        const float cB0 = lo4 ? dj.z : dj.x;
        const float cB1 = lo4 ? dj.w : dj.y;
        const float vB0 = lo4 ? wj.z : wj.x;
        const float vB1 = lo4 ? wj.w : wj.y;
        TB(d4.x, cA0, vA0, b0)
        TB(d4.x, cA1, vA1, b0)
        TB(d4.y, cA0, vA0, b1)
        TB(d4.y, cA1, vA1, b1)
        TB(d4.z, cB0, vB0, b2)
        TB(d4.z, cB1, vB1, b2)
        TB(d4.w, cB0, vB0, b3)
        TB(d4.w, cB1, vB1, b3)
    }

    float nb = w4.x * b0;
    nb = fmaf(w4.y, b1, nb);
    nb = fmaf(w4.z, b2, nb);
    nb = fmaf(w4.w, b3, nb);

    // reduce over the point's 8 lanes
    DPP_ADD(nb, 0xB1)
    DPP_ADD(sq, 0xB1)
    DPP_ADD(nb, 0x4E)
    DPP_ADD(sq, 0x4E)
    nb += __shfl_xor(nb, 4, 64);
    sq += __shfl_xor(sq, 4, 64);

    // pair mass: sum_{i<j} w_i w_j = (1 - sum w^2)/2
    const float den   = fmaxf(0.5f * (1.0f - sq), 0.0f) + EPSF;
    const float ratio = nb * __builtin_amdgcn_rcpf(den);
    const float rho   = 1.0f - exp2f(ratio * (-8.0f * LOG2E));
    if (g == 0) out[p] = rho;
}

extern "C" void kernel_launch(void* const* d_in, const int* in_sizes, int n_in,
                              void* d_out, int out_size, void* d_ws, size_t ws_size,
                              hipStream_t stream) {
    const float* points = (const float*)d_in[0];
    const float* seeds  = (const float*)d_in[1];
    const float* w_raw  = (const float*)d_in[2];
    const float* theta  = (const float*)d_in[3];
    const float* a_raw  = (const float*)d_in[4];
    float* out = (float*)d_out;

    const int N = in_sizes[0] / 2;              // 65536
    const int grid = (N + PPB - 1) / PPB;       // 1024 blocks, 4/CU exact

    voronoi_v17<<<grid, BLOCK, 0, stream>>>(points, seeds, w_raw, theta, a_raw,
                                            out, N);
}